// Round 7
// baseline (5214.967 us; speedup 1.0000x reference)
//
#include <hip/hip_runtime.h>

#define TT 1000
#define FF 20
#define HH 256
#define OO 200
#define ZR 256           // zero-row index in padded int32 tables (257 rows x 256 cols)

typedef unsigned int uint;
typedef unsigned long long ull;

__device__ __forceinline__ int rfl(int v) { return __builtin_amdgcn_readfirstlane(v); }

#define INV30 9.31322574615478515625e-10   // 2^-30, exact in double

// permuted drive slot for column j: 8B lane stride on publish -> clean LDS banking
__device__ __forceinline__ int pidx(int j) { return ((j & 3) << 6) | (j >> 2); }

// One 16/12/8/4-deep batch drawing toggle rows from two 64-bit words (A then B).
// All mask/row/sign math is wave-uniform (scalar pipe); empty slots hit zero row ZR.
// N int4 loads in flight before any use; accumulation exact int64 in registers.
template<int N>
__device__ __forceinline__ void gstep2(const int* __restrict__ tab,
                                       ull& mA, ull cA, int baseA,
                                       ull& mB, ull cB, int baseB,
                                       int cx, long long* acc) {
    const int* p[N];
    int sm[N];
#pragma unroll
    for (int u = 0; u < N; ++u) {
        bool useA = (mA != 0ull);
        ull mm = useA ? mA : mB;
        int bb = __ffsll((unsigned long long)mm);     // 0 if empty
        int k  = (bb ? bb : 1) - 1;
        int row = rfl(mm ? ((useA ? baseA : baseB) + k) : ZR);
        ull cw = useA ? cA : cB;
        int pos = rfl(mm ? (int)((cw >> k) & 1ull) : 1);
        sm[u] = pos ? 0 : -1;
        p[u]  = tab + ((size_t)row << 8);
        if (useA) mA &= (mA - 1ull); else mB &= (mB - 1ull);
    }
    int4 v[N];
#pragma unroll
    for (int u = 0; u < N; ++u) v[u] = *(const int4*)(p[u] + cx);
#pragma unroll
    for (int u = 0; u < N; ++u) {
        acc[0] += (long long)((v[u].x ^ sm[u]) - sm[u]);
        acc[1] += (long long)((v[u].y ^ sm[u]) - sm[u]);
        acc[2] += (long long)((v[u].z ^ sm[u]) - sm[u]);
        acc[3] += (long long)((v[u].w ^ sm[u]) - sm[u]);
    }
}

// Signed toggle gather over two 64-bit words into persistent register acc[4].
__device__ __forceinline__ void gatherT(const int* __restrict__ tab,
                                        ull tA, ull cA, int baseA,
                                        ull tB, ull cB, int baseB,
                                        int cx, long long* acc) {
    while (tA | tB) {
        int pc = rfl((int)(__popcll(tA) + __popcll(tB)));
        if (pc > 12)      gstep2<16>(tab, tA, cA, baseA, tB, cB, baseB, cx, acc);
        else if (pc > 8)  gstep2<12>(tab, tA, cA, baseA, tB, cB, baseB, cx, acc);
        else if (pc > 4)  gstep2<8>(tab, tA, cA, baseA, tB, cB, baseB, cx, acc);
        else              gstep2<4>(tab, tA, cA, baseA, tB, cB, baseB, cx, acc);
    }
}

__global__ __launch_bounds__(1024, 1) void snn_main(
    const float* __restrict__ x,
    const float* __restrict__ W1, const float* __restrict__ b1,
    const float* __restrict__ beta1,
    const float* __restrict__ b2, const float* __restrict__ beta2,
    const int* __restrict__ V1q, const int* __restrict__ V2q,
    const int* __restrict__ W2Tq, const int* __restrict__ WTq,
    const float* __restrict__ alpha_out, const float* __restrict__ beta_out,
    float* __restrict__ out)
{
    __shared__ float w1t_s[FF * HH];     // W1 transposed [f][h]
    __shared__ float wx_s[2][HH];        // b1 + W1 x_t, double-buffered by t parity
    __shared__ float xts[2][FF];         // x[t] double buffer
    __shared__ long long pV1q[2][HH];    // published int64 drives (2 word-pair partials)
    __shared__ long long pV2q[2][HH];    // permuted slot layout (pidx)
    __shared__ long long pW2q[2][HH];
    __shared__ long long pOq[2][HH];
    __shared__ ull m1u[4], t1u[4];       // current + toggle masks, 4x64-bit words
    __shared__ ull m2u[4], t2u[4];

    const int tid = threadIdx.x;
    const int wv  = tid >> 6;
    const int cq  = tid & 63;
    const int b   = blockIdx.x;
    const float* xg = x + (size_t)b * TT * FF;

    // ---- init ----
    for (int idx = tid; idx < FF * HH; idx += 1024) {
        int h = idx / FF, f = idx - h * FF;
        w1t_s[f * HH + h] = W1[idx];
    }
    if (tid < FF) { xts[0][tid] = xg[tid]; xts[1][tid] = xg[FF + tid]; }
    if (tid < 4) { m1u[tid] = 0ull; t1u[tid] = 0ull; m2u[tid] = 0ull; t2u[tid] = 0ull; }
    if (tid < 512) {
        ((long long*)pV1q)[tid] = 0; ((long long*)pV2q)[tid] = 0;
        ((long long*)pW2q)[tid] = 0; ((long long*)pOq)[tid]  = 0;
    }

    // persistent register drive accumulator; role by wave:
    //   wv 0-1: W2T (words 2v,2v+1) | wv 2-3: V2 | wv 4-5: WT | wv 6-7: V1
    long long acc[4] = {0, 0, 0, 0};

    float syn1 = 0.f, mem1 = 0.f, syn2 = 0.f, mem2 = 0.f;
    float b2r = 0.f, beta1r = 0.f, beta2r = 0.f;
    bool spk1 = false, spk2 = false;
    if (tid < HH) { beta1r = beta1[tid]; beta2r = beta2[tid]; b2r = b2[tid]; }
    float b1r2 = 0.f;
    if (tid >= HH && tid < 2 * HH) b1r2 = b1[tid - HH];

    float synO[4] = {0,0,0,0}, memO[4] = {0,0,0,0}, accO[4] = {0,0,0,0};
    float aOr[4] = {0,0,0,0}, bOr[4] = {0,0,0,0};
    bool  spkO[4] = {false,false,false,false};
    if (wv == 15) {
#pragma unroll
        for (int r = 0; r < 4; ++r) {
            int o = cq + (r << 6);
            if (o < OO) { aOr[r] = alpha_out[o]; bOr[r] = beta_out[o]; }
        }
    }
    __syncthreads();
    if (tid < HH) {   // wx for t=0
        float wx = b1[tid];
#pragma unroll
        for (int f = 0; f < FF; ++f) wx = fmaf(xts[0][f], w1t_s[f * HH + tid], wx);
        wx_s[0][tid] = wx;
    }
    __syncthreads();

    for (int t = 0; t < TT; ++t) {
        // ---- B: layer-1 update (waves 0-3); emit m1/t1 word per wave ----
        if (tid < HH) {
            long long a = pV1q[0][pidx(tid)] + pV1q[1][pidx(tid)];
            float g1 = (float)((double)a * INV30);
            syn1 = fmaf(0.95f, syn1, wx_s[t & 1][tid] + g1);
            mem1 = fmaf(beta1r, mem1, syn1) - (spk1 ? 1.f : 0.f);
            spk1 = mem1 > 1.0f;
            ull bal = __ballot(spk1 ? 1 : 0);
            if (cq == 0) { t1u[wv] = m1u[wv] ^ bal; m1u[wv] = bal; }
        }
        __syncthreads();
        // ---- C: W2T gather on t1 (waves 0-1); V2 gather on t2 from D(t-1) (waves 2-3) ----
        if (wv < 2) {
            int v = wv;
            ull tA = t1u[2*v], tB = t1u[2*v+1];
            if (tA | tB) {
                gatherT(W2Tq, tA, m1u[2*v], v*128, tB, m1u[2*v+1], v*128+64, cq << 2, acc);
#pragma unroll
                for (int dj = 0; dj < 4; ++dj) pW2q[v][(dj << 6) | cq] = acc[dj];
            }
        } else if (wv < 4) {
            int v = wv - 2;
            ull tA = t2u[2*v], tB = t2u[2*v+1];
            if (tA | tB) {
                gatherT(V2q, tA, m2u[2*v], v*128, tB, m2u[2*v+1], v*128+64, cq << 2, acc);
#pragma unroll
                for (int dj = 0; dj < 4; ++dj) pV2q[v][(dj << 6) | cq] = acc[dj];
            }
        }
        __syncthreads();
        // ---- D: layer-2 update (waves 0-3) + wx(t+1) (waves 4-7) + x prefetch (wave 8) ----
        if (tid < HH) {
            long long a1 = pW2q[0][pidx(tid)] + pW2q[1][pidx(tid)];
            long long a2 = pV2q[0][pidx(tid)] + pV2q[1][pidx(tid)];
            float gA = (float)((double)a1 * INV30);
            float gB = (float)((double)a2 * INV30);
            syn2 = fmaf(0.95f, syn2, b2r + gA + gB);
            mem2 = fmaf(beta2r, mem2, syn2) - (spk2 ? 1.f : 0.f);
            spk2 = mem2 > 1.0f;
            ull bal = __ballot(spk2 ? 1 : 0);
            if (cq == 0) { t2u[wv] = m2u[wv] ^ bal; m2u[wv] = bal; }
        } else if (tid < 2 * HH) {
            if ((t + 1) < TT) {
                int j2 = tid - HH;
                const float* xx = xts[(t + 1) & 1];
                float wx = b1r2;
#pragma unroll
                for (int f = 0; f < FF; ++f) wx = fmaf(xx[f], w1t_s[f * HH + j2], wx);
                wx_s[(t + 1) & 1][j2] = wx;
            }
        } else if (wv == 8 && cq < FF) {
            if ((t + 2) < TT) xts[t & 1][cq] = xg[(size_t)(t + 2) * FF + cq];
        }
        __syncthreads();
        // ---- E: WT gather on t2 (waves 4-5); V1 gather on t1 (waves 6-7) ----
        if (wv == 4 || wv == 5) {
            int v = wv - 4;
            ull tA = t2u[2*v], tB = t2u[2*v+1];
            if (tA | tB) {
                gatherT(WTq, tA, m2u[2*v], v*128, tB, m2u[2*v+1], v*128+64, cq << 2, acc);
#pragma unroll
                for (int dj = 0; dj < 4; ++dj) pOq[v][(dj << 6) | cq] = acc[dj];
            }
        } else if (wv == 6 || wv == 7) {
            int v = wv - 6;
            ull tA = t1u[2*v], tB = t1u[2*v+1];
            if (tA | tB) {
                gatherT(V1q, tA, m1u[2*v], v*128, tB, m1u[2*v+1], v*128+64, cq << 2, acc);
#pragma unroll
                for (int dj = 0; dj < 4; ++dj) pV1q[v][(dj << 6) | cq] = acc[dj];
            }
        }
        __syncthreads();
        // ---- F: output layer (wave 15; overlaps B/C of t+1) ----
        if (wv == 15) {
            float mmax = -3.402823466e38f;
#pragma unroll
            for (int r = 0; r < 4; ++r) {
                int o = cq + (r << 6);
                if (o < OO) {
                    long long a = pOq[0][pidx(o)] + pOq[1][pidx(o)];
                    float ot = (float)((double)a * INV30);
                    synO[r] = fmaf(aOr[r], synO[r], ot);
                    memO[r] = fmaf(bOr[r], memO[r], synO[r]) - (spkO[r] ? 1.f : 0.f);
                    spkO[r] = memO[r] > 1.0f;
                    mmax = fmaxf(mmax, memO[r]);
                }
            }
#pragma unroll
            for (int off = 32; off; off >>= 1) mmax = fmaxf(mmax, __shfl_xor(mmax, off, 64));
            float ex[4]; float se = 0.f;
#pragma unroll
            for (int r = 0; r < 4; ++r) {
                int o = cq + (r << 6);
                ex[r] = (o < OO) ? expf(memO[r] - mmax) : 0.f;
                se += ex[r];
            }
#pragma unroll
            for (int off = 32; off; off >>= 1) se += __shfl_xor(se, off, 64);
            if (t > 10) {
#pragma unroll
                for (int r = 0; r < 4; ++r) accO[r] += ex[r] / se;
            }
        }
        // no barrier: pOq's next writers (E(t+1), waves 4-5) sit behind D-barrier(t+1),
        // which wave 15 only reaches after finishing F(t).
    }

    if (wv == 15) {
#pragma unroll
        for (int r = 0; r < 4; ++r) {
            int o = cq + (r << 6);
            if (o < OO) out[(size_t)b * OO + o] = accO[r];
        }
    }
}

// one-shot prep: padded 257x256 int32 fixed-point (2^30) tables, zero diagonal
// (V1q/V2q), zero row 256, WTq cols >= 200 zero.
__global__ void prep_kernel(const float* __restrict__ Vrec1, const float* __restrict__ Vrec2,
                            const float* __restrict__ W2, const float* __restrict__ Wout,
                            int* __restrict__ V1q, int* __restrict__ V2q,
                            int* __restrict__ W2Tq, int* __restrict__ WTq) {
    int idx = blockIdx.x * blockDim.x + threadIdx.x;   // 257*256 entries
    if (idx >= 257 * 256) return;
    int r = idx >> 8, c = idx & 255;
    float v1 = 0.f, v2 = 0.f, w2 = 0.f, wo = 0.f;
    if (r < 256) {
        if (r != c) { v1 = Vrec1[r * HH + c]; v2 = Vrec2[r * HH + c]; }
        w2 = W2[c * HH + r];
        if (c < OO) wo = Wout[c * HH + r];
    }
    const float S = 1073741824.0f;   // 2^30
    V1q[idx]  = __float2int_rn(v1 * S);
    V2q[idx]  = __float2int_rn(v2 * S);
    W2Tq[idx] = __float2int_rn(w2 * S);
    WTq[idx]  = __float2int_rn(wo * S);
}

extern "C" void kernel_launch(void* const* d_in, const int* in_sizes, int n_in,
                              void* d_out, int out_size, void* d_ws, size_t ws_size,
                              hipStream_t stream) {
    const float* x       = (const float*)d_in[0];
    const float* W1      = (const float*)d_in[1];
    const float* b1      = (const float*)d_in[2];
    const float* Vrec1   = (const float*)d_in[3];
    const float* beta1   = (const float*)d_in[4];
    const float* W2      = (const float*)d_in[5];
    const float* b2      = (const float*)d_in[6];
    const float* Vrec2   = (const float*)d_in[7];
    const float* beta2   = (const float*)d_in[8];
    const float* Wout    = (const float*)d_in[9];
    const float* alpha_o = (const float*)d_in[10];
    const float* beta_o  = (const float*)d_in[11];

    const int TBL = 257 * 256;       // int32 per padded table
    int* V1q  = (int*)d_ws;
    int* V2q  = V1q + TBL;
    int* W2Tq = V2q + TBL;
    int* WTq  = W2Tq + TBL;          // total ~1.05 MB of ws

    prep_kernel<<<(TBL + 255) / 256, 256, 0, stream>>>(Vrec1, Vrec2, W2, Wout,
                                                       V1q, V2q, W2Tq, WTq);
    snn_main<<<128, 1024, 0, stream>>>(x, W1, b1, beta1, b2, beta2,
                                       V1q, V2q, W2Tq, WTq,
                                       alpha_o, beta_o, (float*)d_out);
}